// Round 1
// baseline (394.123 us; speedup 1.0000x reference)
//
#include <hip/hip_runtime.h>

// Problem constants (reference: N=4, L=2048, H=16, D=32, DIM=512)
#define NB      4
#define L_SEQ   2048
#define H_HEADS 16
#define D32     32
#define DIM     512
#define NH      (NB * H_HEADS)   // 64
#define CHUNK   64
#define NCHUNK  (L_SEQ / CHUNK)  // 32

// ---------------------------------------------------------------------------
// Kernel 1: three GEMMs C = A @ W^T, fused over blockIdx.z.
// A: [8192, 512] row-major (query or key flattened), W: [512,512] row-major.
// Output written directly in (N,H,L,D) layout: dst[((n*16+h)*2048+l)*32+e].
// 64x64 tile, 256 threads, 4x4 microtile, BK=32, LDS stride 33 (pad).
// ---------------------------------------------------------------------------
__global__ __launch_bounds__(256) void gemm3_kernel(
    const float* __restrict__ query, const float* __restrict__ key,
    const float* __restrict__ Wq, const float* __restrict__ Wk,
    const float* __restrict__ Wv,
    float* __restrict__ Qs, float* __restrict__ Ks, float* __restrict__ Vs)
{
    const float* A; const float* W; float* dst;
    int z = blockIdx.z;
    if (z == 0)      { A = query; W = Wq; dst = Qs; }
    else if (z == 1) { A = key;   W = Wk; dst = Ks; }
    else             { A = key;   W = Wv; dst = Vs; }

    __shared__ float Asm[64 * 33];
    __shared__ float Wsm[64 * 33];

    const int t  = threadIdx.x;
    const int r0 = blockIdx.y * 64;   // row tile (0..127)
    const int j0 = blockIdx.x * 64;   // col tile (0..7)
    const int tx = t & 15, ty = t >> 4;

    float acc[4][4] = {{0.f}};

    for (int kb = 0; kb < DIM; kb += 32) {
        // stage tiles: 2 float4 per thread per tile; scalar LDS stores (pad 33)
        #pragma unroll
        for (int i = 0; i < 2; i++) {
            int li  = t + i * 256;
            int row = li >> 3;
            int c0  = (li & 7) * 4;
            float4 av = *(const float4*)(A + (size_t)(r0 + row) * DIM + kb + c0);
            float4 wv4 = *(const float4*)(W + (size_t)(j0 + row) * DIM + kb + c0);
            float* as = &Asm[row * 33 + c0];
            as[0] = av.x; as[1] = av.y; as[2] = av.z; as[3] = av.w;
            float* wsp = &Wsm[row * 33 + c0];
            wsp[0] = wv4.x; wsp[1] = wv4.y; wsp[2] = wv4.z; wsp[3] = wv4.w;
        }
        __syncthreads();
        #pragma unroll
        for (int kk = 0; kk < 32; kk++) {
            float a[4], b[4];
            #pragma unroll
            for (int i = 0; i < 4; i++) a[i] = Asm[(ty * 4 + i) * 33 + kk];
            #pragma unroll
            for (int j = 0; j < 4; j++) b[j] = Wsm[(tx * 4 + j) * 33 + kk];
            #pragma unroll
            for (int i = 0; i < 4; i++)
                #pragma unroll
                for (int j = 0; j < 4; j++)
                    acc[i][j] += a[i] * b[j];
        }
        __syncthreads();
    }

    // epilogue: permuted write into (n,h,l,d)
    #pragma unroll
    for (int i = 0; i < 4; i++) {
        int r = r0 + ty * 4 + i;
        int n = r >> 11, l = r & 2047;
        #pragma unroll
        for (int j = 0; j < 4; j++) {
            int col = j0 + tx * 4 + j;
            int h = col >> 5, e = col & 31;
            dst[(((size_t)(n * H_HEADS + h)) * L_SEQ + l) * D32 + e] = acc[i][j];
        }
    }
}

// ---------------------------------------------------------------------------
// Kernel 2: in-place softmax over contiguous 32-element rows.
// One element per thread; reduce within 32-lane groups of the wave64.
// Launched over Qs and Ks back-to-back (they're contiguous in ws).
// ---------------------------------------------------------------------------
__global__ __launch_bounds__(256) void softmax32_kernel(float* __restrict__ x)
{
    int t = blockIdx.x * 256 + threadIdx.x;
    float v = x[t];
    float m = v;
    #pragma unroll
    for (int off = 16; off > 0; off >>= 1) m = fmaxf(m, __shfl_xor(m, off, 64));
    float ex = __expf(v - m);
    float s = ex;
    #pragma unroll
    for (int off = 16; off > 0; off >>= 1) s += __shfl_xor(s, off, 64);
    x[t] = ex / s;
}

// ---------------------------------------------------------------------------
// Kernel 3: per-chunk KV sums  M_c[d][e] = sum_{l in chunk} k_l[d] * v_l[e]
// grid (NCHUNK, NH), block 256; each thread computes 4 of the 1024 entries.
// ---------------------------------------------------------------------------
__global__ __launch_bounds__(256) void chunk_kv_kernel(
    const float* __restrict__ Ks, const float* __restrict__ Vs,
    float* __restrict__ ckv)
{
    int c = blockIdx.x, nh = blockIdx.y;
    __shared__ float Kc[CHUNK * D32];
    __shared__ float Vc[CHUNK * D32];
    const int t = threadIdx.x;
    size_t base = ((size_t)nh * L_SEQ + (size_t)c * CHUNK) * D32;
    const float4* kp = (const float4*)(Ks + base);
    const float4* vp = (const float4*)(Vs + base);
    ((float4*)Kc)[t]       = kp[t];
    ((float4*)Kc)[t + 256] = kp[t + 256];
    ((float4*)Vc)[t]       = vp[t];
    ((float4*)Vc)[t + 256] = vp[t + 256];
    __syncthreads();

    int d = t >> 3, e0 = (t & 7) * 4;
    float a0 = 0.f, a1 = 0.f, a2 = 0.f, a3 = 0.f;
    #pragma unroll 8
    for (int l = 0; l < CHUNK; l++) {
        float kd = Kc[l * D32 + d];
        const float* vr = &Vc[l * D32 + e0];
        a0 += kd * vr[0]; a1 += kd * vr[1]; a2 += kd * vr[2]; a3 += kd * vr[3];
    }
    float* o = ckv + ((size_t)(nh * NCHUNK + c)) * 1024 + d * D32 + e0;
    o[0] = a0; o[1] = a1; o[2] = a2; o[3] = a3;
}

// ---------------------------------------------------------------------------
// Kernel 4: exclusive prefix over chunks (sequential over 32 chunks, in place).
// grid NH, block 256: thread t owns float4 slot t of the 1024-float state.
// ---------------------------------------------------------------------------
__global__ __launch_bounds__(256) void prefix_kernel(float* __restrict__ ckv)
{
    int nh = blockIdx.x;
    int t  = threadIdx.x;
    float4* base = (float4*)(ckv + (size_t)nh * NCHUNK * 1024) + t;
    float4 acc = make_float4(0.f, 0.f, 0.f, 0.f);
    for (int c = 0; c < NCHUNK; c++) {
        float4* p = base + (size_t)c * 256;
        float4 tmp = *p;
        *p = acc;               // exclusive prefix
        acc.x += tmp.x; acc.y += tmp.y; acc.z += tmp.z; acc.w += tmp.w;
    }
}

// ---------------------------------------------------------------------------
// Kernel 5: per-chunk output
//   out_l = q_l @ S_prev + sum_{l'<=l} (q_l . k_l') v_l'
// grid (NCHUNK, NH), block 256.
// ---------------------------------------------------------------------------
__global__ __launch_bounds__(256) void chunk_out_kernel(
    const float* __restrict__ Qs, const float* __restrict__ Ks,
    const float* __restrict__ Vs, const float* __restrict__ ckv,
    float* __restrict__ out)
{
    int c = blockIdx.x, nh = blockIdx.y;
    __shared__ float Qc[CHUNK * D32];        // l-major, stride 32
    __shared__ float Kc[CHUNK * 36];         // l-major, stride 36 (pad, 16B-aligned)
    __shared__ float Vc[CHUNK * D32];        // l-major, stride 32
    __shared__ float Sp[D32 * D32];          // d-major, stride 32
    __shared__ float P[CHUNK * 66];          // scores, stride 66 (pad)

    const int t = threadIdx.x;
    size_t base = ((size_t)nh * L_SEQ + (size_t)c * CHUNK) * D32;
    const float4* qp = (const float4*)(Qs + base);
    const float4* kp = (const float4*)(Ks + base);
    const float4* vp = (const float4*)(Vs + base);

    ((float4*)Qc)[t]       = qp[t];
    ((float4*)Qc)[t + 256] = qp[t + 256];
    ((float4*)Vc)[t]       = vp[t];
    ((float4*)Vc)[t + 256] = vp[t + 256];
    #pragma unroll
    for (int i = 0; i < 2; i++) {
        int li = t + i * 256;
        int l = li >> 3, d0 = (li & 7) * 4;   // K chunk: padded stride 36
        *(float4*)(&Kc[l * 36 + d0]) = kp[li];
    }
    ((float4*)Sp)[t] = ((const float4*)(ckv + ((size_t)(nh * NCHUNK + c)) * 1024))[t];
    __syncthreads();

    // Phase 1: P[l][lp] = q_l . k_lp for lp<=l else 0.  4096 entries / 256 thr.
    #pragma unroll
    for (int rep = 0; rep < 16; rep++) {
        int idx = rep * 256 + t;
        int l = idx >> 6, lp = idx & 63;
        float s = 0.f;
        if (lp <= l) {
            const float4* q4 = (const float4*)&Qc[l * D32];
            #pragma unroll
            for (int i = 0; i < 8; i++) {
                float4 qv = q4[i];
                float4 kv = *(const float4*)(&Kc[lp * 36 + i * 4]);
                s += qv.x * kv.x + qv.y * kv.y + qv.z * kv.z + qv.w * kv.w;
            }
        }
        P[l * 66 + lp] = s;
    }
    __syncthreads();

    // Phase 2: out[l][e] = sum_d Qc[l][d]*Sp[d][e] + sum_lp P[l][lp]*Vc[lp][e]
    // thread t -> row l = t>>2, e0 = (t&3)*8 (8 outputs, float4-pair)
    int n = nh >> 4, h = nh & 15;
    float* obase = out + ((size_t)n * L_SEQ + (size_t)c * CHUNK) * DIM + h * D32;
    {
        int l  = t >> 2;
        int e0 = (t & 3) * 8;
        float accv[8] = {0.f};
        #pragma unroll
        for (int d = 0; d < D32; d++) {
            float qd = Qc[l * D32 + d];
            float4 s0 = *(const float4*)(&Sp[d * D32 + e0]);
            float4 s1 = *(const float4*)(&Sp[d * D32 + e0 + 4]);
            accv[0] += qd * s0.x; accv[1] += qd * s0.y;
            accv[2] += qd * s0.z; accv[3] += qd * s0.w;
            accv[4] += qd * s1.x; accv[5] += qd * s1.y;
            accv[6] += qd * s1.z; accv[7] += qd * s1.w;
        }
        #pragma unroll
        for (int lp = 0; lp < CHUNK; lp++) {
            float p = P[l * 66 + lp];
            float4 v0 = *(const float4*)(&Vc[lp * D32 + e0]);
            float4 v1 = *(const float4*)(&Vc[lp * D32 + e0 + 4]);
            accv[0] += p * v0.x; accv[1] += p * v0.y;
            accv[2] += p * v0.z; accv[3] += p * v0.w;
            accv[4] += p * v1.x; accv[5] += p * v1.y;
            accv[6] += p * v1.z; accv[7] += p * v1.w;
        }
        float4 o0 = make_float4(accv[0], accv[1], accv[2], accv[3]);
        float4 o1 = make_float4(accv[4], accv[5], accv[6], accv[7]);
        *(float4*)(obase + (size_t)l * DIM + e0)     = o0;
        *(float4*)(obase + (size_t)l * DIM + e0 + 4) = o1;
    }
}

// ---------------------------------------------------------------------------
extern "C" void kernel_launch(void* const* d_in, const int* in_sizes, int n_in,
                              void* d_out, int out_size, void* d_ws, size_t ws_size,
                              hipStream_t stream)
{
    (void)in_sizes; (void)n_in; (void)out_size; (void)ws_size;
    const float* query = (const float*)d_in[0];
    const float* key   = (const float*)d_in[1];
    const float* Wq    = (const float*)d_in[2];
    const float* Wk    = (const float*)d_in[3];
    const float* Wv    = (const float*)d_in[4];
    // d_in[5] = mask (always truthy -> causal path); unused.
    float* out = (float*)d_out;

    // workspace layout (floats):
    //   Qs : NH*L*32 = 4,194,304
    //   Ks : 4,194,304   (contiguous after Qs — softmax runs over Qs..Ks)
    //   Vs : 4,194,304
    //   ckv: NH*NCHUNK*1024 = 2,097,152
    // total 58.7 MB
    float* ws  = (float*)d_ws;
    const size_t SZ = (size_t)NH * L_SEQ * D32;
    float* Qs  = ws;
    float* Ks  = Qs + SZ;
    float* Vs  = Ks + SZ;
    float* ckv = Vs + SZ;

    dim3 blk(256);
    // 1) projections: rows 8192/64=128, cols 512/64=8, z=3 matrices
    gemm3_kernel<<<dim3(8, 128, 3), blk, 0, stream>>>(query, key, Wq, Wk, Wv,
                                                      Qs, Ks, Vs);
    // 2) softmax on Qs and Ks (contiguous): 2*NH*L rows of 32 -> 8,388,608 thr
    softmax32_kernel<<<dim3((2 * SZ) / 256), blk, 0, stream>>>(Qs);
    // 3) per-chunk KV sums
    chunk_kv_kernel<<<dim3(NCHUNK, NH), blk, 0, stream>>>(Ks, Vs, ckv);
    // 4) exclusive prefix over chunks
    prefix_kernel<<<dim3(NH), blk, 0, stream>>>(ckv);
    // 5) chunk outputs
    chunk_out_kernel<<<dim3(NCHUNK, NH), blk, 0, stream>>>(Qs, Ks, Vs, ckv, out);
}

// Round 2
// 167.173 us; speedup vs baseline: 2.3576x; 2.3576x over previous
//
#include <hip/hip_runtime.h>

// Problem constants (reference: N=4, L=2048, H=16, D=32, DIM=512)
#define NB      4
#define L_SEQ   2048
#define H_HEADS 16
#define D32     32
#define DIM     512
#define NH      (NB * H_HEADS)   // 64
#define CHUNK   64
#define NCHUNK  (L_SEQ / CHUNK)  // 32

typedef __attribute__((ext_vector_type(8))) short bf16x8;
typedef __attribute__((ext_vector_type(4))) float f32x4;

// f32 -> bf16 round-to-nearest-even (inputs are finite normals)
__device__ __forceinline__ unsigned short f2bf(float x) {
    unsigned u = __float_as_uint(x);
    u += 0x7fff + ((u >> 16) & 1);
    return (unsigned short)(u >> 16);
}
__device__ __forceinline__ unsigned pack2(float lo, float hi) {
    return (unsigned)f2bf(lo) | ((unsigned)f2bf(hi) << 16);
}

// ---------------------------------------------------------------------------
// Kernel 1: three GEMMs C = A @ W^T via bf16 MFMA, fused over blockIdx.z,
// with softmax over D=32 head-groups fused into the epilogue for z<2 (Q,K).
// A: [8192,512] f32 row-major; W: [512,512] f32 row-major (both K-contiguous
// -> both operands load with the identical A-style fragment layout, giving
// A·W^T directly).
// Tile 128x128xBK32, 256 threads = 4 waves, each wave a 64x64 subtile
// (4x4 grid of 16x16x32 MFMA). LDS tiles stored in MFMA-fragment chunk
// order: chunk li = row*4 + (k>>3) at byte offset li*16 -> staging ds_write
// and fragment ds_read are both permutations of contiguous 16B chunks
// (conflict-free).
// ---------------------------------------------------------------------------
__global__ __launch_bounds__(256) void gemm3_mfma_kernel(
    const float* __restrict__ query, const float* __restrict__ key,
    const float* __restrict__ Wq, const float* __restrict__ Wk,
    const float* __restrict__ Wv,
    float* __restrict__ Qs, float* __restrict__ Ks, float* __restrict__ Vs)
{
    const float* A; const float* W; float* dst;
    const int z = blockIdx.z;
    if (z == 0)      { A = query; W = Wq; dst = Qs; }
    else if (z == 1) { A = key;   W = Wk; dst = Ks; }
    else             { A = key;   W = Wv; dst = Vs; }

    __shared__ short Asm[128 * 32];   // 8 KB, fragment-chunk order
    __shared__ short Wsm[128 * 32];   // 8 KB

    const int t    = threadIdx.x;
    const int r0   = blockIdx.y * 128;   // A row tile
    const int j0   = blockIdx.x * 128;   // output col tile (W row tile)
    const int w    = t >> 6;
    const int lane = t & 63;
    const int wm   = w >> 1, wn = w & 1;
    // fragment chunk offset (shorts): lane -> row=lane&15, kq=lane>>4
    const int chunkoff = ((lane & 15) * 4 + (lane >> 4)) * 8;

    f32x4 acc[4][4] = {};

    for (int kb = 0; kb < DIM; kb += 32) {
        // ---- stage both tiles: thread handles chunks li = t, t+256 per tile
        #pragma unroll
        for (int rep = 0; rep < 2; rep++) {
            int li  = t + rep * 256;
            int row = li >> 2, kq = li & 3;
            const float* ga = A + (size_t)(r0 + row) * DIM + kb + kq * 8;
            const float* gw = W + (size_t)(j0 + row) * DIM + kb + kq * 8;
            float4 a0 = *(const float4*)ga;
            float4 a1 = *(const float4*)(ga + 4);
            float4 w0 = *(const float4*)gw;
            float4 w1 = *(const float4*)(gw + 4);
            ((uint4*)Asm)[li] = make_uint4(pack2(a0.x, a0.y), pack2(a0.z, a0.w),
                                           pack2(a1.x, a1.y), pack2(a1.z, a1.w));
            ((uint4*)Wsm)[li] = make_uint4(pack2(w0.x, w0.y), pack2(w0.z, w0.w),
                                           pack2(w1.x, w1.y), pack2(w1.z, w1.w));
        }
        __syncthreads();

        bf16x8 af[4], bfr[4];
        #pragma unroll
        for (int i = 0; i < 4; i++)
            af[i] = *(const bf16x8*)(Asm + (wm * 4 + i) * 512 + chunkoff);
        #pragma unroll
        for (int j = 0; j < 4; j++)
            bfr[j] = *(const bf16x8*)(Wsm + (wn * 4 + j) * 512 + chunkoff);
        #pragma unroll
        for (int i = 0; i < 4; i++)
            #pragma unroll
            for (int j = 0; j < 4; j++)
                acc[i][j] = __builtin_amdgcn_mfma_f32_16x16x32_bf16(
                    af[i], bfr[j], acc[i][j], 0, 0, 0);
        __syncthreads();
    }

    // ---- fused softmax over D=32 head groups (Q and K only) ----
    // C/D frag: col = lane&15, row = (lane>>4)*4 + reg. A head = 32 cols =
    // accumulator pair (2jp, 2jp+1); row values live in 16 lanes (same quad),
    // so xor-shuffles with masks 1,2,4,8 reduce within the row.
    if (z < 2) {
        #pragma unroll
        for (int i = 0; i < 4; i++)
            #pragma unroll
            for (int jp = 0; jp < 2; jp++)
                #pragma unroll
                for (int r = 0; r < 4; r++) {
                    float a = acc[i][2 * jp][r], b = acc[i][2 * jp + 1][r];
                    float m = fmaxf(a, b);
                    #pragma unroll
                    for (int off = 1; off < 16; off <<= 1)
                        m = fmaxf(m, __shfl_xor(m, off, 64));
                    float ea = __expf(a - m), eb = __expf(b - m);
                    float s = ea + eb;
                    #pragma unroll
                    for (int off = 1; off < 16; off <<= 1)
                        s += __shfl_xor(s, off, 64);
                    float inv = 1.0f / s;
                    acc[i][2 * jp][r]     = ea * inv;
                    acc[i][2 * jp + 1][r] = eb * inv;
                }
    }

    // ---- epilogue: permuted write into (n,h,l,d) f32 ----
    const int quad = lane >> 4, lc = lane & 15;
    #pragma unroll
    for (int i = 0; i < 4; i++) {
        int rbase = r0 + wm * 64 + i * 16 + quad * 4;
        #pragma unroll
        for (int r = 0; r < 4; r++) {
            int rg = rbase + r;
            int n = rg >> 11, l = rg & 2047;
            #pragma unroll
            for (int j = 0; j < 4; j++) {
                int cg = j0 + wn * 64 + j * 16 + lc;
                int h = cg >> 5, e = cg & 31;
                dst[(((size_t)(n * H_HEADS + h)) * L_SEQ + l) * D32 + e] =
                    acc[i][j][r];
            }
        }
    }
}

// ---------------------------------------------------------------------------
// Kernel 3: per-chunk KV sums  M_c[d][e] = sum_{l in chunk} k_l[d] * v_l[e]
// ---------------------------------------------------------------------------
__global__ __launch_bounds__(256) void chunk_kv_kernel(
    const float* __restrict__ Ks, const float* __restrict__ Vs,
    float* __restrict__ ckv)
{
    int c = blockIdx.x, nh = blockIdx.y;
    __shared__ float Kc[CHUNK * D32];
    __shared__ float Vc[CHUNK * D32];
    const int t = threadIdx.x;
    size_t base = ((size_t)nh * L_SEQ + (size_t)c * CHUNK) * D32;
    const float4* kp = (const float4*)(Ks + base);
    const float4* vp = (const float4*)(Vs + base);
    ((float4*)Kc)[t]       = kp[t];
    ((float4*)Kc)[t + 256] = kp[t + 256];
    ((float4*)Vc)[t]       = vp[t];
    ((float4*)Vc)[t + 256] = vp[t + 256];
    __syncthreads();

    int d = t >> 3, e0 = (t & 7) * 4;
    float a0 = 0.f, a1 = 0.f, a2 = 0.f, a3 = 0.f;
    #pragma unroll 8
    for (int l = 0; l < CHUNK; l++) {
        float kd = Kc[l * D32 + d];
        const float* vr = &Vc[l * D32 + e0];
        a0 += kd * vr[0]; a1 += kd * vr[1]; a2 += kd * vr[2]; a3 += kd * vr[3];
    }
    float* o = ckv + ((size_t)(nh * NCHUNK + c)) * 1024 + d * D32 + e0;
    o[0] = a0; o[1] = a1; o[2] = a2; o[3] = a3;
}

// ---------------------------------------------------------------------------
// Kernel 4: exclusive prefix over 32 chunks, in place. Batched loads: all 32
// issued independently up front (one latency period), scan in-register.
// ---------------------------------------------------------------------------
__global__ __launch_bounds__(256) void prefix_kernel(float* __restrict__ ckv)
{
    int nh = blockIdx.x;
    int t  = threadIdx.x;
    float4* base = (float4*)(ckv + (size_t)nh * NCHUNK * 1024) + t;
    float4 vals[NCHUNK];
    #pragma unroll
    for (int c = 0; c < NCHUNK; c++) vals[c] = base[(size_t)c * 256];
    float4 acc = make_float4(0.f, 0.f, 0.f, 0.f);
    #pragma unroll
    for (int c = 0; c < NCHUNK; c++) {
        float4 tmp = vals[c];
        base[(size_t)c * 256] = acc;
        acc.x += tmp.x; acc.y += tmp.y; acc.z += tmp.z; acc.w += tmp.w;
    }
}

// ---------------------------------------------------------------------------
// Kernel 5: per-chunk output
//   out_l = q_l @ S_prev + sum_{l'<=l} (q_l . k_l') v_l'
// ---------------------------------------------------------------------------
__global__ __launch_bounds__(256) void chunk_out_kernel(
    const float* __restrict__ Qs, const float* __restrict__ Ks,
    const float* __restrict__ Vs, const float* __restrict__ ckv,
    float* __restrict__ out)
{
    int c = blockIdx.x, nh = blockIdx.y;
    __shared__ float Qc[CHUNK * D32];        // l-major, stride 32
    __shared__ float Kc[CHUNK * 36];         // l-major, stride 36 (pad)
    __shared__ float Vc[CHUNK * D32];        // l-major, stride 32
    __shared__ float Sp[D32 * D32];          // d-major, stride 32
    __shared__ float P[CHUNK * 66];          // scores, stride 66 (pad)

    const int t = threadIdx.x;
    size_t base = ((size_t)nh * L_SEQ + (size_t)c * CHUNK) * D32;
    const float4* qp = (const float4*)(Qs + base);
    const float4* kp = (const float4*)(Ks + base);
    const float4* vp = (const float4*)(Vs + base);

    ((float4*)Qc)[t]       = qp[t];
    ((float4*)Qc)[t + 256] = qp[t + 256];
    ((float4*)Vc)[t]       = vp[t];
    ((float4*)Vc)[t + 256] = vp[t + 256];
    #pragma unroll
    for (int i = 0; i < 2; i++) {
        int li = t + i * 256;
        int l = li >> 3, d0 = (li & 7) * 4;
        *(float4*)(&Kc[l * 36 + d0]) = kp[li];
    }
    ((float4*)Sp)[t] = ((const float4*)(ckv + ((size_t)(nh * NCHUNK + c)) * 1024))[t];
    __syncthreads();

    // Phase 1: P[l][lp] = q_l . k_lp for lp<=l else 0.
    #pragma unroll
    for (int rep = 0; rep < 16; rep++) {
        int idx = rep * 256 + t;
        int l = idx >> 6, lp = idx & 63;
        float s = 0.f;
        if (lp <= l) {
            const float4* q4 = (const float4*)&Qc[l * D32];
            #pragma unroll
            for (int i = 0; i < 8; i++) {
                float4 qv = q4[i];
                float4 kv = *(const float4*)(&Kc[lp * 36 + i * 4]);
                s += qv.x * kv.x + qv.y * kv.y + qv.z * kv.z + qv.w * kv.w;
            }
        }
        P[l * 66 + lp] = s;
    }
    __syncthreads();

    // Phase 2: out[l][e] = sum_d Qc[l][d]*Sp[d][e] + sum_lp P[l][lp]*Vc[lp][e]
    int n = nh >> 4, h = nh & 15;
    float* obase = out + ((size_t)n * L_SEQ + (size_t)c * CHUNK) * DIM + h * D32;
    {
        int l  = t >> 2;
        int e0 = (t & 3) * 8;
        float accv[8] = {0.f};
        #pragma unroll
        for (int d = 0; d < D32; d++) {
            float qd = Qc[l * D32 + d];
            float4 s0 = *(const float4*)(&Sp[d * D32 + e0]);
            float4 s1 = *(const float4*)(&Sp[d * D32 + e0 + 4]);
            accv[0] += qd * s0.x; accv[1] += qd * s0.y;
            accv[2] += qd * s0.z; accv[3] += qd * s0.w;
            accv[4] += qd * s1.x; accv[5] += qd * s1.y;
            accv[6] += qd * s1.z; accv[7] += qd * s1.w;
        }
        #pragma unroll
        for (int lp = 0; lp < CHUNK; lp++) {
            float p = P[l * 66 + lp];
            float4 v0 = *(const float4*)(&Vc[lp * D32 + e0]);
            float4 v1 = *(const float4*)(&Vc[lp * D32 + e0 + 4]);
            accv[0] += p * v0.x; accv[1] += p * v0.y;
            accv[2] += p * v0.z; accv[3] += p * v0.w;
            accv[4] += p * v1.x; accv[5] += p * v1.y;
            accv[6] += p * v1.z; accv[7] += p * v1.w;
        }
        float4 o0 = make_float4(accv[0], accv[1], accv[2], accv[3]);
        float4 o1 = make_float4(accv[4], accv[5], accv[6], accv[7]);
        *(float4*)(obase + (size_t)l * DIM + e0)     = o0;
        *(float4*)(obase + (size_t)l * DIM + e0 + 4) = o1;
    }
}

// ---------------------------------------------------------------------------
extern "C" void kernel_launch(void* const* d_in, const int* in_sizes, int n_in,
                              void* d_out, int out_size, void* d_ws, size_t ws_size,
                              hipStream_t stream)
{
    (void)in_sizes; (void)n_in; (void)out_size; (void)ws_size;
    const float* query = (const float*)d_in[0];
    const float* key   = (const float*)d_in[1];
    const float* Wq    = (const float*)d_in[2];
    const float* Wk    = (const float*)d_in[3];
    const float* Wv    = (const float*)d_in[4];
    float* out = (float*)d_out;

    float* ws  = (float*)d_ws;
    const size_t SZ = (size_t)NH * L_SEQ * D32;
    float* Qs  = ws;
    float* Ks  = Qs + SZ;
    float* Vs  = Ks + SZ;
    float* ckv = Vs + SZ;

    dim3 blk(256);
    // 1) projections + fused softmax: cols 512/128=4, rows 8192/128=64, z=3
    gemm3_mfma_kernel<<<dim3(4, 64, 3), blk, 0, stream>>>(query, key,
                                                          Wq, Wk, Wv,
                                                          Qs, Ks, Vs);
    // 2) per-chunk KV sums
    chunk_kv_kernel<<<dim3(NCHUNK, NH), blk, 0, stream>>>(Ks, Vs, ckv);
    // 3) exclusive prefix over chunks
    prefix_kernel<<<dim3(NH), blk, 0, stream>>>(ckv);
    // 4) chunk outputs
    chunk_out_kernel<<<dim3(NCHUNK, NH), blk, 0, stream>>>(Qs, Ks, Vs, ckv, out);
}

// Round 3
// 165.312 us; speedup vs baseline: 2.3841x; 1.0113x over previous
//
#include <hip/hip_runtime.h>

// Problem constants (reference: N=4, L=2048, H=16, D=32, DIM=512)
#define NB      4
#define L_SEQ   2048
#define H_HEADS 16
#define D32     32
#define DIM     512
#define NH      (NB * H_HEADS)   // 64
#define CHUNK   64
#define NCHUNK  (L_SEQ / CHUNK)  // 32

typedef __attribute__((ext_vector_type(8))) short bf16x8;
typedef __attribute__((ext_vector_type(4))) float f32x4;

// f32 -> bf16 round-to-nearest-even (inputs are finite normals)
__device__ __forceinline__ unsigned short f2bf(float x) {
    unsigned u = __float_as_uint(x);
    u += 0x7fff + ((u >> 16) & 1);
    return (unsigned short)(u >> 16);
}
__device__ __forceinline__ unsigned pack2(float lo, float hi) {
    return (unsigned)f2bf(lo) | ((unsigned)f2bf(hi) << 16);
}

// ---------------------------------------------------------------------------
// Kernel 1: three GEMMs C = A @ W^T via bf16 MFMA, fused over blockIdx.z,
// softmax over D=32 head-groups fused into the epilogue for Q,K.
// Outputs (bf16):
//   z=0: Qs  [nh][l][d]            (l-major)
//   z=1: Ks  [nh][l][d]  AND  Kt [nh][d][l]  (both layouts)
//   z=2: Vt  [nh][d][l]            (d-major only)
// ---------------------------------------------------------------------------
__global__ __launch_bounds__(256) void gemm3_mfma_kernel(
    const float* __restrict__ query, const float* __restrict__ key,
    const float* __restrict__ Wq, const float* __restrict__ Wk,
    const float* __restrict__ Wv,
    unsigned short* __restrict__ Qs, unsigned short* __restrict__ Ks,
    unsigned short* __restrict__ Kt, unsigned short* __restrict__ Vt)
{
    const float* A; const float* W;
    const int z = blockIdx.z;
    if (z == 0)      { A = query; W = Wq; }
    else if (z == 1) { A = key;   W = Wk; }
    else             { A = key;   W = Wv; }

    __shared__ short Asm[128 * 32];   // 8 KB, fragment-chunk order
    __shared__ short Wsm[128 * 32];   // 8 KB

    const int t    = threadIdx.x;
    const int r0   = blockIdx.y * 128;   // A row tile
    const int j0   = blockIdx.x * 128;   // output col tile (W row tile)
    const int w    = t >> 6;
    const int lane = t & 63;
    const int wm   = w >> 1, wn = w & 1;
    const int chunkoff = ((lane & 15) * 4 + (lane >> 4)) * 8;

    f32x4 acc[4][4] = {};

    for (int kb = 0; kb < DIM; kb += 32) {
        #pragma unroll
        for (int rep = 0; rep < 2; rep++) {
            int li  = t + rep * 256;
            int row = li >> 2, kq = li & 3;
            const float* ga = A + (size_t)(r0 + row) * DIM + kb + kq * 8;
            const float* gw = W + (size_t)(j0 + row) * DIM + kb + kq * 8;
            float4 a0 = *(const float4*)ga;
            float4 a1 = *(const float4*)(ga + 4);
            float4 w0 = *(const float4*)gw;
            float4 w1 = *(const float4*)(gw + 4);
            ((uint4*)Asm)[li] = make_uint4(pack2(a0.x, a0.y), pack2(a0.z, a0.w),
                                           pack2(a1.x, a1.y), pack2(a1.z, a1.w));
            ((uint4*)Wsm)[li] = make_uint4(pack2(w0.x, w0.y), pack2(w0.z, w0.w),
                                           pack2(w1.x, w1.y), pack2(w1.z, w1.w));
        }
        __syncthreads();

        bf16x8 af[4], bfr[4];
        #pragma unroll
        for (int i = 0; i < 4; i++)
            af[i] = *(const bf16x8*)(Asm + (wm * 4 + i) * 512 + chunkoff);
        #pragma unroll
        for (int j = 0; j < 4; j++)
            bfr[j] = *(const bf16x8*)(Wsm + (wn * 4 + j) * 512 + chunkoff);
        #pragma unroll
        for (int i = 0; i < 4; i++)
            #pragma unroll
            for (int j = 0; j < 4; j++)
                acc[i][j] = __builtin_amdgcn_mfma_f32_16x16x32_bf16(
                    af[i], bfr[j], acc[i][j], 0, 0, 0);
        __syncthreads();
    }

    // fused softmax over D=32 head groups (Q and K only)
    if (z < 2) {
        #pragma unroll
        for (int i = 0; i < 4; i++)
            #pragma unroll
            for (int jp = 0; jp < 2; jp++)
                #pragma unroll
                for (int r = 0; r < 4; r++) {
                    float a = acc[i][2 * jp][r], b = acc[i][2 * jp + 1][r];
                    float m = fmaxf(a, b);
                    #pragma unroll
                    for (int off = 1; off < 16; off <<= 1)
                        m = fmaxf(m, __shfl_xor(m, off, 64));
                    float ea = __expf(a - m), eb = __expf(b - m);
                    float s = ea + eb;
                    #pragma unroll
                    for (int off = 1; off < 16; off <<= 1)
                        s += __shfl_xor(s, off, 64);
                    float inv = 1.0f / s;
                    acc[i][2 * jp][r]     = ea * inv;
                    acc[i][2 * jp + 1][r] = eb * inv;
                }
    }

    // epilogue: bf16 writes in the layouts downstream MFMA fragments want
    const int quad = lane >> 4, lc = lane & 15;
    #pragma unroll
    for (int i = 0; i < 4; i++) {
        int rbase = r0 + wm * 64 + i * 16 + quad * 4;
        #pragma unroll
        for (int r = 0; r < 4; r++) {
            int rg = rbase + r;
            int n = rg >> 11, l = rg & 2047;
            #pragma unroll
            for (int j = 0; j < 4; j++) {
                int cg = j0 + wn * 64 + j * 16 + lc;
                int h = cg >> 5, e = cg & 31;
                int nh = n * H_HEADS + h;
                unsigned short val = f2bf(acc[i][j][r]);
                if (z == 0) {
                    Qs[((size_t)nh * L_SEQ + l) * D32 + e] = val;
                } else if (z == 1) {
                    Ks[((size_t)nh * L_SEQ + l) * D32 + e] = val;
                    Kt[((size_t)nh * D32 + e) * L_SEQ + l] = val;
                } else {
                    Vt[((size_t)nh * D32 + e) * L_SEQ + l] = val;
                }
            }
        }
    }
}

// ---------------------------------------------------------------------------
// Kernel 2: per-chunk KV sums via MFMA, transposed form:
//   ckvT[e][d] = sum_l V[l][e] * K[l][d]  =  (V^T)·(K^T)^T
// A = Vt rows (e, l-contig), X = Kt rows (d, l-contig): direct global frags.
// One wave per (c,nh); block = 4 chunks of one nh. No LDS.
// ---------------------------------------------------------------------------
__global__ __launch_bounds__(256) void chunk_kv_mfma_kernel(
    const unsigned short* __restrict__ Kt, const unsigned short* __restrict__ Vt,
    float* __restrict__ ckvT)
{
    const int nh = blockIdx.y;
    const int c  = blockIdx.x * 4 + (threadIdx.x >> 6);
    const int lane = threadIdx.x & 63;
    const int lm = lane & 15, quad = lane >> 4;

    f32x4 acc[2][2] = {};
    #pragma unroll
    for (int ch = 0; ch < 2; ch++) {
        bf16x8 aV[2], bK[2];
        #pragma unroll
        for (int mt = 0; mt < 2; mt++)
            aV[mt] = *(const bf16x8*)(Vt + ((size_t)nh * D32 + mt * 16 + lm) * L_SEQ
                                         + c * CHUNK + ch * 32 + quad * 8);
        #pragma unroll
        for (int nt = 0; nt < 2; nt++)
            bK[nt] = *(const bf16x8*)(Kt + ((size_t)nh * D32 + nt * 16 + lm) * L_SEQ
                                         + c * CHUNK + ch * 32 + quad * 8);
        #pragma unroll
        for (int mt = 0; mt < 2; mt++)
            #pragma unroll
            for (int nt = 0; nt < 2; nt++)
                acc[mt][nt] = __builtin_amdgcn_mfma_f32_16x16x32_bf16(
                    aV[mt], bK[nt], acc[mt][nt], 0, 0, 0);
    }
    // C frag: col = lane&15 -> d, row = quad*4+r -> e
    #pragma unroll
    for (int mt = 0; mt < 2; mt++)
        #pragma unroll
        for (int nt = 0; nt < 2; nt++)
            #pragma unroll
            for (int r = 0; r < 4; r++) {
                int e = mt * 16 + quad * 4 + r;
                int d = nt * 16 + lm;
                ckvT[(((size_t)nh * NCHUNK + c) * 32 + e) * 32 + d] = acc[mt][nt][r];
            }
}

// ---------------------------------------------------------------------------
// Kernel 3: exclusive prefix over 32 chunks; reads ckvT f32, writes SpT bf16.
// ---------------------------------------------------------------------------
__global__ __launch_bounds__(256) void prefix_kernel(
    const float* __restrict__ ckvT, unsigned short* __restrict__ SpT)
{
    int nh = blockIdx.x;
    int t  = threadIdx.x;
    const float4* base = (const float4*)(ckvT + (size_t)nh * NCHUNK * 1024) + t;
    float4 vals[NCHUNK];
    #pragma unroll
    for (int c = 0; c < NCHUNK; c++) vals[c] = base[(size_t)c * 256];
    float4 acc = make_float4(0.f, 0.f, 0.f, 0.f);
    unsigned short* sp = SpT + (size_t)nh * NCHUNK * 1024 + t * 4;
    #pragma unroll
    for (int c = 0; c < NCHUNK; c++) {
        ushort4 u;
        u.x = f2bf(acc.x); u.y = f2bf(acc.y);
        u.z = f2bf(acc.z); u.w = f2bf(acc.w);
        *(ushort4*)(sp + (size_t)c * 1024) = u;   // exclusive prefix
        acc.x += vals[c].x; acc.y += vals[c].y;
        acc.z += vals[c].z; acc.w += vals[c].w;
    }
}

// ---------------------------------------------------------------------------
// Kernel 4: per-chunk output, MFMA:
//   P = tril(Qc Kc^T)            (phase A, bf16 P staged in LDS)
//   O = Qc·SpT^T + P·Vt^T        (phase B)
// Wave w owns rows [w*16, w*16+16). All A/B frags except P are direct global
// loads. LDS = P only (64x72 bf16, 9 KB).
// ---------------------------------------------------------------------------
__global__ __launch_bounds__(256) void chunk_out_mfma_kernel(
    const unsigned short* __restrict__ Qs, const unsigned short* __restrict__ Ks,
    const unsigned short* __restrict__ Vt, const unsigned short* __restrict__ SpT,
    float* __restrict__ out)
{
    const int c = blockIdx.x, nh = blockIdx.y;
    __shared__ unsigned short P[64 * 72];   // row l, col l', stride 72

    const int t = threadIdx.x, w = t >> 6, lane = t & 63;
    const int lm = lane & 15, quad = lane >> 4;

    // A-frag of Q for rows w*16+lm (shared by phase A and phase B)
    bf16x8 aQ = *(const bf16x8*)(Qs + ((size_t)nh * L_SEQ + c * CHUNK + w * 16 + lm) * D32
                                    + quad * 8);

    // ---- Phase A: P tiles j=0..3 (j>w stored as zeros) ----
    #pragma unroll
    for (int j = 0; j < 4; j++) {
        f32x4 p = {};
        if (j <= w) {
            bf16x8 bK = *(const bf16x8*)(Ks + ((size_t)nh * L_SEQ + c * CHUNK + j * 16 + lm) * D32
                                            + quad * 8);
            p = __builtin_amdgcn_mfma_f32_16x16x32_bf16(aQ, bK, p, 0, 0, 0);
            if (j == w) {
                #pragma unroll
                for (int r = 0; r < 4; r++)
                    if (lm > quad * 4 + r) p[r] = 0.f;   // causal: keep l' <= l
            }
        }
        #pragma unroll
        for (int r = 0; r < 4; r++)
            P[(w * 16 + quad * 4 + r) * 72 + j * 16 + lm] = f2bf(p[r]);
    }
    __syncthreads();

    // ---- Phase B: O rows w*16.., cols e in two 16-tiles ----
    const int chains = (w < 2) ? 1 : 2;
    bf16x8 aP[2];
    for (int ch = 0; ch < chains; ch++)
        aP[ch] = *(const bf16x8*)&P[(w * 16 + lm) * 72 + ch * 32 + quad * 8];

    const int n = nh >> 4, h = nh & 15;
    #pragma unroll
    for (int nt = 0; nt < 2; nt++) {
        bf16x8 bS = *(const bf16x8*)(SpT + (((size_t)nh * NCHUNK + c) * 32 + nt * 16 + lm) * 32
                                         + quad * 8);
        f32x4 acc = {};
        acc = __builtin_amdgcn_mfma_f32_16x16x32_bf16(aQ, bS, acc, 0, 0, 0);
        for (int ch = 0; ch < chains; ch++) {
            bf16x8 bV = *(const bf16x8*)(Vt + ((size_t)nh * D32 + nt * 16 + lm) * L_SEQ
                                            + c * CHUNK + ch * 32 + quad * 8);
            acc = __builtin_amdgcn_mfma_f32_16x16x32_bf16(aP[ch], bV, acc, 0, 0, 0);
        }
        #pragma unroll
        for (int r = 0; r < 4; r++) {
            int lg = c * CHUNK + w * 16 + quad * 4 + r;
            out[((size_t)n * L_SEQ + lg) * DIM + h * D32 + nt * 16 + lm] = acc[r];
        }
    }
}

// ---------------------------------------------------------------------------
extern "C" void kernel_launch(void* const* d_in, const int* in_sizes, int n_in,
                              void* d_out, int out_size, void* d_ws, size_t ws_size,
                              hipStream_t stream)
{
    (void)in_sizes; (void)n_in; (void)out_size; (void)ws_size;
    const float* query = (const float*)d_in[0];
    const float* key   = (const float*)d_in[1];
    const float* Wq    = (const float*)d_in[2];
    const float* Wk    = (const float*)d_in[3];
    const float* Wv    = (const float*)d_in[4];
    float* out = (float*)d_out;

    // workspace layout:
    //   Qs,Ks,Kt,Vt : bf16, SZ each (8.4 MB each)
    //   ckvT        : f32, NH*NCHUNK*1024 (8.4 MB)
    //   SpT         : bf16, NH*NCHUNK*1024 (4.2 MB)
    const size_t SZ = (size_t)NH * L_SEQ * D32;
    unsigned short* Qs = (unsigned short*)d_ws;
    unsigned short* Ks = Qs + SZ;
    unsigned short* Kt = Ks + SZ;
    unsigned short* Vt = Kt + SZ;
    float* ckvT        = (float*)(Vt + SZ);
    unsigned short* SpT = (unsigned short*)(ckvT + (size_t)NH * NCHUNK * 1024);

    dim3 blk(256);
    gemm3_mfma_kernel<<<dim3(4, 64, 3), blk, 0, stream>>>(query, key, Wq, Wk, Wv,
                                                          Qs, Ks, Kt, Vt);
    chunk_kv_mfma_kernel<<<dim3(NCHUNK / 4, NH), blk, 0, stream>>>(Kt, Vt, ckvT);
    prefix_kernel<<<dim3(NH), blk, 0, stream>>>(ckvT, SpT);
    chunk_out_mfma_kernel<<<dim3(NCHUNK, NH), blk, 0, stream>>>(Qs, Ks, Vt, SpT, out);
}